// Round 1
// baseline (263.398 us; speedup 1.0000x reference)
//
#include <hip/hip_runtime.h>
#include <hip/hip_bf16.h>

#define NB 2
#define ND 256
#define NE 2048
#define NH 4
#define NDK 64
#define MAXP 8

typedef __attribute__((ext_vector_type(8))) short bf16x8;
typedef __attribute__((ext_vector_type(4))) float f32x4;

static __device__ __forceinline__ short f2b(float f) {
    union { __hip_bfloat16 h; short s; } u;
    u.h = __float2bfloat16(f);
    return u.s;
}

static __device__ __forceinline__ f32x4 mfma16(bf16x8 a, bf16x8 b, f32x4 c) {
    return __builtin_amdgcn_mfma_f32_16x16x32_bf16(a, b, c, 0, 0, 0);
}

// ---------------- transpose x [B,D,E] -> s [B*E, D] ----------------
__global__ void k_transpose_x(const float* __restrict__ x, float* __restrict__ s) {
    __shared__ float tile[32][33];
    int b = blockIdx.z;
    int e0 = blockIdx.x * 32, d0 = blockIdx.y * 32;
    int tx = threadIdx.x, ty = threadIdx.y; // (32, 8)
    #pragma unroll
    for (int r = 0; r < 4; r++) {
        int dd = ty + r * 8;
        tile[dd][tx] = x[((size_t)b * ND + d0 + dd) * NE + e0 + tx];
    }
    __syncthreads();
    #pragma unroll
    for (int r = 0; r < 4; r++) {
        int ee = ty + r * 8;
        s[((size_t)b * NE + e0 + ee) * ND + d0 + tx] = tile[tx][ee];
    }
}

// ---------------- layernorm rows of s -> qn ----------------
__global__ __launch_bounds__(256) void k_layernorm(const float* __restrict__ s,
        const float* __restrict__ g, const float* __restrict__ bb,
        float* __restrict__ qn) {
    int row = blockIdx.x;
    int t = threadIdx.x, wave = t >> 6, lane = t & 63;
    __shared__ float red[4];
    float v = s[(size_t)row * ND + t];
    float sum = v;
    #pragma unroll
    for (int off = 32; off; off >>= 1) sum += __shfl_xor(sum, off);
    if (lane == 0) red[wave] = sum;
    __syncthreads();
    float mean = (red[0] + red[1] + red[2] + red[3]) * (1.0f / ND);
    __syncthreads();
    float d = v - mean;
    float sq = d * d;
    #pragma unroll
    for (int off = 32; off; off >>= 1) sq += __shfl_xor(sq, off);
    if (lane == 0) red[wave] = sq;
    __syncthreads();
    float var = (red[0] + red[1] + red[2] + red[3]) * (1.0f / ND);
    qn[(size_t)row * ND + t] = d * rsqrtf(var + 1e-6f) * g[t] + bb[t];
}

// ---------------- SGEMM C = A[4096,256] @ W[256,256]^T, modes ----------------
// MODE 0: q  -> scale 1/8, write f32 outF and bf16 outB
// MODE 1: k/v-> write bf16 outB
// MODE 2: fc -> add resid, write transposed f32 to xout [B,D,E]
template<int MODE>
__global__ __launch_bounds__(256) void k_gemm(const float* __restrict__ A,
        const float* __restrict__ W, float* __restrict__ outF,
        short* __restrict__ outB, const float* __restrict__ resid,
        float* __restrict__ xout) {
    __shared__ float As[16][65], Bs[16][65];
    int m0 = blockIdx.x * 64, n0 = blockIdx.y * 64;
    int t = threadIdx.x;
    int lr = t >> 2, lc = (t & 3) * 4;
    int tm = (t >> 4) * 4, tn = (t & 15) * 4;
    float acc[4][4] = {};
    for (int k0 = 0; k0 < 256; k0 += 16) {
        f32x4 av = *(const f32x4*)&A[(size_t)(m0 + lr) * 256 + k0 + lc];
        f32x4 wv = *(const f32x4*)&W[(size_t)(n0 + lr) * 256 + k0 + lc];
        #pragma unroll
        for (int j = 0; j < 4; j++) { As[lc + j][lr] = av[j]; Bs[lc + j][lr] = wv[j]; }
        __syncthreads();
        #pragma unroll
        for (int k = 0; k < 16; k++) {
            float a[4], b[4];
            #pragma unroll
            for (int i = 0; i < 4; i++) { a[i] = As[k][tm + i]; b[i] = Bs[k][tn + i]; }
            #pragma unroll
            for (int i = 0; i < 4; i++)
                #pragma unroll
                for (int j = 0; j < 4; j++) acc[i][j] += a[i] * b[j];
        }
        __syncthreads();
    }
    #pragma unroll
    for (int i = 0; i < 4; i++) {
        int row = m0 + tm + i;
        #pragma unroll
        for (int j = 0; j < 4; j++) {
            int col = n0 + tn + j;
            float val = acc[i][j];
            if (MODE == 0) {
                val *= 0.125f;
                outF[(size_t)row * 256 + col] = val;
                outB[(size_t)row * 256 + col] = f2b(val);
            } else if (MODE == 1) {
                outB[(size_t)row * 256 + col] = f2b(val);
            } else {
                val += resid[(size_t)row * 256 + col];
                int b = row >> 11, e = row & (NE - 1);
                xout[(size_t)b * ND * NE + (size_t)col * NE + e] = val;
            }
        }
    }
}

// ---------------- transpose vbf [B*E,256] -> vtb [B*H, 64, E] ----------------
__global__ void k_transpose_v(const short* __restrict__ vbf, short* __restrict__ vtb) {
    __shared__ short tile[32][33];
    int bh = blockIdx.z, b = bh >> 2, h = bh & 3;
    int e0 = blockIdx.x * 32, dv0 = blockIdx.y * 32;
    int tx = threadIdx.x, ty = threadIdx.y; // (32,8)
    #pragma unroll
    for (int r = 0; r < 4; r++) {
        int ee = ty + r * 8;
        tile[ee][tx] = vbf[(size_t)(b * NE + e0 + ee) * 256 + h * 64 + dv0 + tx];
    }
    __syncthreads();
    #pragma unroll
    for (int r = 0; r < 4; r++) {
        int dv = ty + r * 8;
        vtb[((size_t)bh * 64 + dv0 + dv) * NE + e0 + tx] = tile[tx][dv];
    }
}

// ---------------- q . rpr table -> qdr [B*E, H, 9] ----------------
__global__ __launch_bounds__(256) void k_qdr(const float* __restrict__ qf,
        const float* __restrict__ w_rpr, float* __restrict__ qdr) {
    int row = blockIdx.x;
    int t = threadIdx.x;
    int h = t >> 6, d = t & 63;
    float qv = qf[(size_t)row * 256 + h * 64 + d];
    #pragma unroll
    for (int p = 0; p <= MAXP; p++) {
        float prod = qv * w_rpr[p * 64 + d];
        #pragma unroll
        for (int off = 32; off; off >>= 1) prod += __shfl_xor(prod, off);
        if (d == 0) qdr[((size_t)row * NH + h) * 9 + p] = prod;
    }
}

// ---------------- scores: raw masked scores -> a region ----------------
__global__ __launch_bounds__(256) void k_scores(const short* __restrict__ qbf,
        const short* __restrict__ kbf, const int* __restrict__ dist,
        const float* __restrict__ qdr, float* __restrict__ a_out) {
    int t = threadIdx.x;
    int wave = t >> 6, lane = t & 63;
    int l16 = lane & 15, lk = (lane >> 4) * 8;
    int bh = blockIdx.z, b = bh >> 2, h = bh & 3;
    int m0 = blockIdx.x * 64 + wave * 16;
    int n0 = blockIdx.y * 64;
    const short* Abase = qbf + (size_t)(b * NE + m0 + l16) * 256 + h * 64 + lk;
    f32x4 acc[4];
    f32x4 z = {0.f, 0.f, 0.f, 0.f};
    #pragma unroll
    for (int c = 0; c < 4; c++) acc[c] = z;
    #pragma unroll
    for (int kk = 0; kk < 64; kk += 32) {
        bf16x8 av = *(const bf16x8*)(Abase + kk);
        #pragma unroll
        for (int c = 0; c < 4; c++) {
            bf16x8 bv = *(const bf16x8*)(kbf +
                (size_t)(b * NE + n0 + c * 16 + l16) * 256 + h * 64 + kk + lk);
            acc[c] = mfma16(av, bv, acc[c]);
        }
    }
    int rbase = m0 + (lane >> 4) * 4;
    #pragma unroll
    for (int c = 0; c < 4; c++) {
        int col = n0 + c * 16 + l16;
        #pragma unroll
        for (int r = 0; r < 4; r++) {
            int row = rbase + r;
            float val = acc[c][r];
            int dd = dist[(size_t)(b * NE + row) * NE + col];
            int pos = dd < MAXP ? dd : MAXP;
            val += qdr[((size_t)(b * NE + row) * NH + h) * 9 + pos];
            if (dd > MAXP) val = -1e9f;
            a_out[((size_t)bh * NE + row) * NE + col] = val;
        }
    }
}

// ---------------- softmax rows of a in place ----------------
__global__ __launch_bounds__(256) void k_softmax(float* __restrict__ a) {
    size_t base = (size_t)blockIdx.x * NE;
    int t = threadIdx.x, wave = t >> 6, lane = t & 63;
    __shared__ float red[4];
    f32x4 v0 = *(f32x4*)&a[base + t * 4];
    f32x4 v1 = *(f32x4*)&a[base + 1024 + t * 4];
    float m = v0[0];
    #pragma unroll
    for (int j = 0; j < 4; j++) { m = fmaxf(m, v0[j]); m = fmaxf(m, v1[j]); }
    #pragma unroll
    for (int off = 32; off; off >>= 1) m = fmaxf(m, __shfl_xor(m, off));
    if (lane == 0) red[wave] = m;
    __syncthreads();
    m = fmaxf(fmaxf(red[0], red[1]), fmaxf(red[2], red[3]));
    __syncthreads();
    float ssum = 0.f;
    #pragma unroll
    for (int j = 0; j < 4; j++) {
        v0[j] = __expf(v0[j] - m); ssum += v0[j];
        v1[j] = __expf(v1[j] - m); ssum += v1[j];
    }
    #pragma unroll
    for (int off = 32; off; off >>= 1) ssum += __shfl_xor(ssum, off);
    if (lane == 0) red[wave] = ssum;
    __syncthreads();
    float inv = 1.0f / (red[0] + red[1] + red[2] + red[3]);
    #pragma unroll
    for (int j = 0; j < 4; j++) { v0[j] *= inv; v1[j] *= inv; }
    *(f32x4*)&a[base + t * 4] = v0;
    *(f32x4*)&a[base + 1024 + t * 4] = v1;
}

// ---------------- PV: out_attn[B*E, 256] = a @ V ----------------
__global__ __launch_bounds__(256) void k_pv(const float* __restrict__ a_out,
        const short* __restrict__ vtb, float* __restrict__ out_attn) {
    int t = threadIdx.x, wave = t >> 6, lane = t & 63;
    int l16 = lane & 15, lk8 = (lane >> 4) * 8;
    int bh = blockIdx.z, b = bh >> 2, h = bh & 3;
    int m0 = blockIdx.x * 64 + wave * 16;
    const float* Abase = a_out + ((size_t)bh * NE + m0 + l16) * NE + lk8;
    const short* Bbase = vtb + ((size_t)bh * 64 + l16) * NE + lk8;
    f32x4 acc[4];
    f32x4 z = {0.f, 0.f, 0.f, 0.f};
    #pragma unroll
    for (int c = 0; c < 4; c++) acc[c] = z;
    for (int kk = 0; kk < NE; kk += 32) {
        f32x4 a0 = *(const f32x4*)(Abase + kk);
        f32x4 a1 = *(const f32x4*)(Abase + kk + 4);
        bf16x8 av;
        #pragma unroll
        for (int j = 0; j < 4; j++) { av[j] = f2b(a0[j]); av[4 + j] = f2b(a1[j]); }
        #pragma unroll
        for (int c = 0; c < 4; c++) {
            bf16x8 bv = *(const bf16x8*)(Bbase + (size_t)c * 16 * NE + kk);
            acc[c] = mfma16(av, bv, acc[c]);
        }
    }
    int rbase = m0 + (lane >> 4) * 4;
    #pragma unroll
    for (int c = 0; c < 4; c++)
        #pragma unroll
        for (int r = 0; r < 4; r++)
            out_attn[(size_t)(b * NE + rbase + r) * 256 + h * 64 + c * 16 + l16] = acc[c][r];
}

extern "C" void kernel_launch(void* const* d_in, const int* in_sizes, int n_in,
                              void* d_out, int out_size, void* d_ws, size_t ws_size,
                              hipStream_t stream) {
    const float* x    = (const float*)d_in[0];
    const int*   dist = (const int*)d_in[1];
    const float* w_qs = (const float*)d_in[2];
    const float* w_ks = (const float*)d_in[3];
    const float* w_vs = (const float*)d_in[4];
    const float* w_fc = (const float*)d_in[5];
    const float* w_rpr= (const float*)d_in[6];
    const float* ln_g = (const float*)d_in[7];
    const float* ln_b = (const float*)d_in[8];

    char* ws = (char*)d_ws;
    float* s    = (float*)(ws);
    float* qn   = (float*)(ws + (4u << 20));
    float* qf   = (float*)(ws + (8u << 20));
    float* oat  = (float*)(ws + (12u << 20));
    short* qbf  = (short*)(ws + (16u << 20));
    short* kbf  = (short*)(ws + (18u << 20));
    short* vbf  = (short*)(ws + (20u << 20));
    short* vtb  = (short*)(ws + (22u << 20));
    float* qdr  = (float*)(ws + (24u << 20));

    float* xout  = (float*)d_out;
    float* a_out = xout + (size_t)NB * ND * NE;

    k_transpose_x<<<dim3(NE / 32, ND / 32, NB), dim3(32, 8), 0, stream>>>(x, s);
    k_layernorm<<<dim3(NB * NE), dim3(256), 0, stream>>>(s, ln_g, ln_b, qn);
    k_gemm<0><<<dim3(64, 4), dim3(256), 0, stream>>>(qn, w_qs, qf, qbf, nullptr, nullptr);
    k_gemm<1><<<dim3(64, 4), dim3(256), 0, stream>>>(s, w_ks, nullptr, kbf, nullptr, nullptr);
    k_gemm<1><<<dim3(64, 4), dim3(256), 0, stream>>>(s, w_vs, nullptr, vbf, nullptr, nullptr);
    k_transpose_v<<<dim3(NE / 32, 2, NB * NH), dim3(32, 8), 0, stream>>>(vbf, vtb);
    k_qdr<<<dim3(NB * NE), dim3(256), 0, stream>>>(qf, w_rpr, qdr);
    k_scores<<<dim3(NE / 64, NE / 64, NB * NH), dim3(256), 0, stream>>>(qbf, kbf, dist, qdr, a_out);
    k_softmax<<<dim3(NB * NH * NE), dim3(256), 0, stream>>>(a_out);
    k_pv<<<dim3(NE / 64, 1, NB * NH), dim3(256), 0, stream>>>(a_out, vtb, oat);
    k_gemm<2><<<dim3(64, 4), dim3(256), 0, stream>>>(oat, w_fc, nullptr, nullptr, s, xout);
}

// Round 2
// 211.680 us; speedup vs baseline: 1.2443x; 1.2443x over previous
//
#include <hip/hip_runtime.h>
#include <hip/hip_bf16.h>

#define NB 2
#define ND 256
#define NE 2048
#define NH 4
#define NDK 64
#define MAXP 8

typedef __attribute__((ext_vector_type(8))) short bf16x8;
typedef __attribute__((ext_vector_type(4))) float f32x4;

static __device__ __forceinline__ short f2b(float f) {
    union { __hip_bfloat16 h; short s; } u;
    u.h = __float2bfloat16(f);
    return u.s;
}

static __device__ __forceinline__ float b2f(short s) {
    union { unsigned int u; float f; } u;
    u.u = ((unsigned int)(unsigned short)s) << 16;
    return u.f;
}

static __device__ __forceinline__ f32x4 mfma16(bf16x8 a, bf16x8 b, f32x4 c) {
    return __builtin_amdgcn_mfma_f32_16x16x32_bf16(a, b, c, 0, 0, 0);
}

// ---------------- transpose x [B,D,E] -> s [B*E, D] ----------------
__global__ void k_transpose_x(const float* __restrict__ x, float* __restrict__ s) {
    __shared__ float tile[32][33];
    int b = blockIdx.z;
    int e0 = blockIdx.x * 32, d0 = blockIdx.y * 32;
    int tx = threadIdx.x, ty = threadIdx.y; // (32, 8)
    #pragma unroll
    for (int r = 0; r < 4; r++) {
        int dd = ty + r * 8;
        tile[dd][tx] = x[((size_t)b * ND + d0 + dd) * NE + e0 + tx];
    }
    __syncthreads();
    #pragma unroll
    for (int r = 0; r < 4; r++) {
        int ee = ty + r * 8;
        s[((size_t)b * NE + e0 + ee) * ND + d0 + tx] = tile[tx][ee];
    }
}

// ---------------- layernorm rows of s -> qn ----------------
__global__ __launch_bounds__(256) void k_layernorm(const float* __restrict__ s,
        const float* __restrict__ g, const float* __restrict__ bb,
        float* __restrict__ qn) {
    int row = blockIdx.x;
    int t = threadIdx.x, wave = t >> 6, lane = t & 63;
    __shared__ float red[4];
    float v = s[(size_t)row * ND + t];
    float sum = v;
    #pragma unroll
    for (int off = 32; off; off >>= 1) sum += __shfl_xor(sum, off);
    if (lane == 0) red[wave] = sum;
    __syncthreads();
    float mean = (red[0] + red[1] + red[2] + red[3]) * (1.0f / ND);
    __syncthreads();
    float d = v - mean;
    float sq = d * d;
    #pragma unroll
    for (int off = 32; off; off >>= 1) sq += __shfl_xor(sq, off);
    if (lane == 0) red[wave] = sq;
    __syncthreads();
    float var = (red[0] + red[1] + red[2] + red[3]) * (1.0f / ND);
    qn[(size_t)row * ND + t] = d * rsqrtf(var + 1e-6f) * g[t] + bb[t];
}

// ---------------- SGEMM C = A[4096,256] @ W[256,256]^T, modes ----------------
template<int MODE>
__global__ __launch_bounds__(256) void k_gemm(const float* __restrict__ A,
        const float* __restrict__ W, float* __restrict__ outF,
        short* __restrict__ outB, const float* __restrict__ resid,
        float* __restrict__ xout) {
    __shared__ float As[16][65], Bs[16][65];
    int m0 = blockIdx.x * 64, n0 = blockIdx.y * 64;
    int t = threadIdx.x;
    int lr = t >> 2, lc = (t & 3) * 4;
    int tm = (t >> 4) * 4, tn = (t & 15) * 4;
    float acc[4][4] = {};
    for (int k0 = 0; k0 < 256; k0 += 16) {
        f32x4 av = *(const f32x4*)&A[(size_t)(m0 + lr) * 256 + k0 + lc];
        f32x4 wv = *(const f32x4*)&W[(size_t)(n0 + lr) * 256 + k0 + lc];
        #pragma unroll
        for (int j = 0; j < 4; j++) { As[lc + j][lr] = av[j]; Bs[lc + j][lr] = wv[j]; }
        __syncthreads();
        #pragma unroll
        for (int k = 0; k < 16; k++) {
            float a[4], b[4];
            #pragma unroll
            for (int i = 0; i < 4; i++) { a[i] = As[k][tm + i]; b[i] = Bs[k][tn + i]; }
            #pragma unroll
            for (int i = 0; i < 4; i++)
                #pragma unroll
                for (int j = 0; j < 4; j++) acc[i][j] += a[i] * b[j];
        }
        __syncthreads();
    }
    #pragma unroll
    for (int i = 0; i < 4; i++) {
        int row = m0 + tm + i;
        #pragma unroll
        for (int j = 0; j < 4; j++) {
            int col = n0 + tn + j;
            float val = acc[i][j];
            if (MODE == 0) {
                val *= 0.125f;
                outF[(size_t)row * 256 + col] = val;
                outB[(size_t)row * 256 + col] = f2b(val);
            } else if (MODE == 1) {
                outB[(size_t)row * 256 + col] = f2b(val);
            } else {
                val += resid[(size_t)row * 256 + col];
                int b = row >> 11, e = row & (NE - 1);
                xout[(size_t)b * ND * NE + (size_t)col * NE + e] = val;
            }
        }
    }
}

// ---------------- transpose vbf [B*E,256] -> vtb [B*H, 64, E] ----------------
__global__ void k_transpose_v(const short* __restrict__ vbf, short* __restrict__ vtb) {
    __shared__ short tile[32][33];
    int bh = blockIdx.z, b = bh >> 2, h = bh & 3;
    int e0 = blockIdx.x * 32, dv0 = blockIdx.y * 32;
    int tx = threadIdx.x, ty = threadIdx.y; // (32,8)
    #pragma unroll
    for (int r = 0; r < 4; r++) {
        int ee = ty + r * 8;
        tile[ee][tx] = vbf[(size_t)(b * NE + e0 + ee) * 256 + h * 64 + dv0 + tx];
    }
    __syncthreads();
    #pragma unroll
    for (int r = 0; r < 4; r++) {
        int dv = ty + r * 8;
        vtb[((size_t)bh * 64 + dv0 + dv) * NE + e0 + tx] = tile[tx][dv];
    }
}

// ---------------- q . rpr table -> qdr [B*E, H, 9] ----------------
__global__ __launch_bounds__(256) void k_qdr(const float* __restrict__ qf,
        const float* __restrict__ w_rpr, float* __restrict__ qdr) {
    int row = blockIdx.x;
    int t = threadIdx.x;
    int h = t >> 6, d = t & 63;
    float qv = qf[(size_t)row * 256 + h * 64 + d];
    #pragma unroll
    for (int p = 0; p <= MAXP; p++) {
        float prod = qv * w_rpr[p * 64 + d];
        #pragma unroll
        for (int off = 32; off; off >>= 1) prod += __shfl_xor(prod, off);
        if (d == 0) qdr[((size_t)row * NH + h) * 9 + p] = prod;
    }
}

// ---------------- fused scores+softmax+PV, writes a (once) and oat ----------
// grid: (NE/64, NB*NH), block 512 (8 waves). Wave w = ph*4 + rg:
//   rg picks the 16-row strip, ph∈{0,1} picks the column-tile phase.
__global__ __launch_bounds__(512) void k_attn(
        const short* __restrict__ qbf, const short* __restrict__ kbf,
        const int* __restrict__ dist, const float* __restrict__ qdr,
        const short* __restrict__ vtb, float* __restrict__ a_out,
        float* __restrict__ oat) {
    __shared__ float qdr_lds[64][9];
    __shared__ short plds[8][16][72];
    __shared__ float comb[8][16][2];
    __shared__ float pvcomb[4][16][64];

    int t = threadIdx.x;
    int wave = t >> 6, lane = t & 63;
    int l16 = lane & 15, g = lane >> 4;
    int lk = g * 8;
    int bh = blockIdx.y, b = bh >> 2, h = bh & 3;
    int rg = wave & 3, ph = wave >> 2;
    int m0w = blockIdx.x * 64 + rg * 16;
    int rbase = m0w + g * 4;
    int rowL = rg * 16 + g * 4;  // row within block (qdr_lds index)

    // stage qdr bias rows for this block
    int m0blk = blockIdx.x * 64;
    for (int i = t; i < 576; i += 512) {
        int row = i / 9, p = i - row * 9;
        qdr_lds[row][p] = qdr[((size_t)(b * NE + m0blk + row) * NH + h) * 9 + p];
    }
    __syncthreads();

    // q fragments: invariant over tiles
    const short* Abase = qbf + (size_t)(b * NE + m0w + l16) * 256 + h * 64 + lk;
    bf16x8 aq0 = *(const bf16x8*)(Abase);
    bf16x8 aq1 = *(const bf16x8*)(Abase + 32);

    const int* distb = dist + (size_t)(b * NE + rbase) * NE;

    float rmax[4] = {-1e30f, -1e30f, -1e30f, -1e30f};
    float rsum[4] = {0.f, 0.f, 0.f, 0.f};

    // ---------------- pass 1: online (max,sum) ----------------
    for (int j = 0; j < 16; j++) {
        int n0 = (ph + 2 * j) * 64;
        f32x4 acc[4];
        f32x4 z = {0.f, 0.f, 0.f, 0.f};
        #pragma unroll
        for (int c = 0; c < 4; c++) acc[c] = z;
        #pragma unroll
        for (int c = 0; c < 4; c++) {
            const short* Bb = kbf + (size_t)(b * NE + n0 + c * 16 + l16) * 256 + h * 64 + lk;
            bf16x8 bv0 = *(const bf16x8*)(Bb);
            bf16x8 bv1 = *(const bf16x8*)(Bb + 32);
            acc[c] = mfma16(aq0, bv0, acc[c]);
            acc[c] = mfma16(aq1, bv1, acc[c]);
        }
        float val[4][4];
        #pragma unroll
        for (int c = 0; c < 4; c++) {
            int col = n0 + c * 16 + l16;
            #pragma unroll
            for (int r = 0; r < 4; r++) {
                int dd = distb[(size_t)r * NE + col];
                int pos = dd < MAXP ? dd : MAXP;
                float v = acc[c][r] + qdr_lds[rowL + r][pos];
                val[c][r] = dd > MAXP ? -1e9f : v;
            }
        }
        #pragma unroll
        for (int r = 0; r < 4; r++) {
            float tm = fmaxf(fmaxf(val[0][r], val[1][r]), fmaxf(val[2][r], val[3][r]));
            #pragma unroll
            for (int off = 8; off; off >>= 1) tm = fmaxf(tm, __shfl_xor(tm, off));
            float nm = fmaxf(rmax[r], tm);
            float ts = 0.f;
            #pragma unroll
            for (int c = 0; c < 4; c++) ts += __expf(val[c][r] - nm);
            #pragma unroll
            for (int off = 8; off; off >>= 1) ts += __shfl_xor(ts, off);
            rsum[r] = rsum[r] * __expf(rmax[r] - nm) + ts;
            rmax[r] = nm;
        }
    }

    // combine stats across the wave pair
    if (l16 == 0) {
        #pragma unroll
        for (int r = 0; r < 4; r++) {
            comb[wave][g * 4 + r][0] = rmax[r];
            comb[wave][g * 4 + r][1] = rsum[r];
        }
    }
    __syncthreads();
    {
        int pw = ((ph ^ 1) << 2) + rg;
        #pragma unroll
        for (int r = 0; r < 4; r++) {
            float m2 = comb[pw][g * 4 + r][0];
            float s2 = comb[pw][g * 4 + r][1];
            float nm = fmaxf(rmax[r], m2);
            rsum[r] = rsum[r] * __expf(rmax[r] - nm) + s2 * __expf(m2 - nm);
            rmax[r] = nm;
        }
    }
    float rinv[4];
    #pragma unroll
    for (int r = 0; r < 4; r++) rinv[r] = 1.0f / rsum[r];

    // ---------------- pass 2: normalize, write a, PV ----------------
    f32x4 accp[4];
    {
        f32x4 z = {0.f, 0.f, 0.f, 0.f};
        #pragma unroll
        for (int c = 0; c < 4; c++) accp[c] = z;
    }
    for (int j = 0; j < 16; j++) {
        int n0 = (ph + 2 * j) * 64;
        f32x4 acc[4];
        f32x4 z = {0.f, 0.f, 0.f, 0.f};
        #pragma unroll
        for (int c = 0; c < 4; c++) acc[c] = z;
        #pragma unroll
        for (int c = 0; c < 4; c++) {
            const short* Bb = kbf + (size_t)(b * NE + n0 + c * 16 + l16) * 256 + h * 64 + lk;
            bf16x8 bv0 = *(const bf16x8*)(Bb);
            bf16x8 bv1 = *(const bf16x8*)(Bb + 32);
            acc[c] = mfma16(aq0, bv0, acc[c]);
            acc[c] = mfma16(aq1, bv1, acc[c]);
        }
        #pragma unroll
        for (int c = 0; c < 4; c++) {
            int col = n0 + c * 16 + l16;
            #pragma unroll
            for (int r = 0; r < 4; r++) {
                int dd = distb[(size_t)r * NE + col];
                int pos = dd < MAXP ? dd : MAXP;
                float v = acc[c][r] + qdr_lds[rowL + r][pos];
                v = dd > MAXP ? -1e9f : v;
                float p = __expf(v - rmax[r]) * rinv[r];
                plds[wave][g * 4 + r][c * 16 + l16] = f2b(p);
            }
        }
        // PV MFMA from wave-local LDS tile (wave-synchronous, no barrier)
        bf16x8 pa0 = *(const bf16x8*)&plds[wave][l16][lk];
        bf16x8 pa1 = *(const bf16x8*)&plds[wave][l16][32 + lk];
        #pragma unroll
        for (int c = 0; c < 4; c++) {
            const short* Vb = vtb + ((size_t)bh * 64 + c * 16 + l16) * NE + n0 + lk;
            bf16x8 bv0 = *(const bf16x8*)(Vb);
            bf16x8 bv1 = *(const bf16x8*)(Vb + 32);
            accp[c] = mfma16(pa0, bv0, accp[c]);
            accp[c] = mfma16(pa1, bv1, accp[c]);
        }
        // coalesced a_out store: 16 rows x 64 cols f32, 256B per row
        #pragma unroll
        for (int r4 = 0; r4 < 4; r4++) {
            int row = r4 * 4 + g;
            short4 pv = *(const short4*)&plds[wave][row][l16 * 4];
            f32x4 o;
            o[0] = b2f(pv.x); o[1] = b2f(pv.y); o[2] = b2f(pv.z); o[3] = b2f(pv.w);
            *(f32x4*)&a_out[((size_t)bh * NE + m0w + row) * NE + n0 + l16 * 4] = o;
        }
    }

    // combine PV partials across the wave pair, store oat
    __syncthreads();
    if (ph == 1) {
        #pragma unroll
        for (int c = 0; c < 4; c++)
            #pragma unroll
            for (int r = 0; r < 4; r++)
                pvcomb[rg][g * 4 + r][c * 16 + l16] = accp[c][r];
    }
    __syncthreads();
    if (ph == 0) {
        #pragma unroll
        for (int c = 0; c < 4; c++) {
            #pragma unroll
            for (int r = 0; r < 4; r++) {
                float v = accp[c][r] + pvcomb[rg][g * 4 + r][c * 16 + l16];
                oat[(size_t)(b * NE + rbase + r) * 256 + h * 64 + c * 16 + l16] = v;
            }
        }
    }
}

extern "C" void kernel_launch(void* const* d_in, const int* in_sizes, int n_in,
                              void* d_out, int out_size, void* d_ws, size_t ws_size,
                              hipStream_t stream) {
    const float* x    = (const float*)d_in[0];
    const int*   dist = (const int*)d_in[1];
    const float* w_qs = (const float*)d_in[2];
    const float* w_ks = (const float*)d_in[3];
    const float* w_vs = (const float*)d_in[4];
    const float* w_fc = (const float*)d_in[5];
    const float* w_rpr= (const float*)d_in[6];
    const float* ln_g = (const float*)d_in[7];
    const float* ln_b = (const float*)d_in[8];

    char* ws = (char*)d_ws;
    float* s    = (float*)(ws);
    float* qn   = (float*)(ws + (4u << 20));
    float* qf   = (float*)(ws + (8u << 20));
    float* oat  = (float*)(ws + (12u << 20));
    short* qbf  = (short*)(ws + (16u << 20));
    short* kbf  = (short*)(ws + (18u << 20));
    short* vbf  = (short*)(ws + (20u << 20));
    short* vtb  = (short*)(ws + (22u << 20));
    float* qdr  = (float*)(ws + (24u << 20));

    float* xout  = (float*)d_out;
    float* a_out = xout + (size_t)NB * ND * NE;

    k_transpose_x<<<dim3(NE / 32, ND / 32, NB), dim3(32, 8), 0, stream>>>(x, s);
    k_layernorm<<<dim3(NB * NE), dim3(256), 0, stream>>>(s, ln_g, ln_b, qn);
    k_gemm<0><<<dim3(64, 4), dim3(256), 0, stream>>>(qn, w_qs, qf, qbf, nullptr, nullptr);
    k_gemm<1><<<dim3(64, 4), dim3(256), 0, stream>>>(s, w_ks, nullptr, kbf, nullptr, nullptr);
    k_gemm<1><<<dim3(64, 4), dim3(256), 0, stream>>>(s, w_vs, nullptr, vbf, nullptr, nullptr);
    k_transpose_v<<<dim3(NE / 32, 2, NB * NH), dim3(32, 8), 0, stream>>>(vbf, vtb);
    k_qdr<<<dim3(NB * NE), dim3(256), 0, stream>>>(qf, w_rpr, qdr);
    k_attn<<<dim3(NE / 64, NB * NH), dim3(512), 0, stream>>>(qbf, kbf, dist, qdr, vtb, a_out, oat);
    k_gemm<2><<<dim3(64, 4), dim3(256), 0, stream>>>(oat, w_fc, nullptr, nullptr, s, xout);
}